// Round 1
// baseline (286.745 us; speedup 1.0000x reference)
//
#include <hip/hip_runtime.h>
#include <math.h>

#define B_DIM 4096
#define T_DIM 4096

constexpr float GAMMA_F = 0.99f;
constexpr float CLIP_V  = 5.0f;

// constexpr-folded gamma powers (each step rounds once; drift ~1e-7 rel)
constexpr float G2    = GAMMA_F * GAMMA_F; // g^2
constexpr float G4    = G2 * G2;           // g^4
constexpr float G8    = G4 * G4;           // g^8
constexpr float Q1    = G8 * G8;           // g^16
constexpr float Q2    = Q1 * Q1;           // g^32
constexpr float Q4    = Q2 * Q2;           // g^64
constexpr float Q8    = Q4 * Q4;           // g^128
constexpr float Q16   = Q8 * Q8;           // g^256
constexpr float Q32   = Q16 * Q16;         // g^512
constexpr float G1024 = Q32 * Q32;         // g^1024

// g^(16*e) for e in [0,63] via binary exponentiation (exact-ish, deterministic)
__device__ __forceinline__ float pow_g16(int e) {
    float f = 1.0f;
    if (e & 1)  f *= Q1;
    if (e & 2)  f *= Q2;
    if (e & 4)  f *= Q4;
    if (e & 8)  f *= Q8;
    if (e & 16) f *= Q16;
    if (e & 32) f *= Q32;
    return f;
}

// ---------------------------------------------------------------------------
// K1: per-row reverse discounted scan.
// One block (256 thr) per row. Thread i owns elements [i*16, i*16+16).
// 3-level scan: in-thread (16, registers) -> in-wave (64 lanes, shuffles,
// factors g^(16*off)) -> cross-wave (4 waves, Horner with g^1024).
// LDS padded idx+(idx>>4): per-thread chunk reads at lane stride 17 floats
// -> 2-way bank aliasing only (free).
// ---------------------------------------------------------------------------
__global__ __launch_bounds__(256) void k_scan(const float* __restrict__ logits,
                                              const float* __restrict__ weight,
                                              float* __restrict__ cum) {
    __shared__ float buf[4352]; // 4096 + 256 pad
    __shared__ float waveS[4];

    const int row = blockIdx.x;
    const int tid = threadIdx.x;
    const size_t base = (size_t)row * T_DIM;

    // coalesced load + wr = weight * log_sigmoid(logits)
    #pragma unroll
    for (int j = 0; j < 16; ++j) {
        int idx = j * 256 + tid;
        float x = logits[base + idx];
        float w = weight[base + idx];
        float ls = fminf(x, 0.0f) - log1pf(__expf(-fabsf(x)));
        buf[idx + (idx >> 4)] = w * ls;
    }
    __syncthreads();

    // in-thread: load chunk to regs, discounted suffix sum V = sum g^j wr[j]
    float wr[16];
    const int pbase = tid * 17;
    #pragma unroll
    for (int j = 0; j < 16; ++j) wr[j] = buf[pbase + j];
    float V = 0.0f;
    #pragma unroll
    for (int j = 15; j >= 0; --j) V = fmaf(GAMMA_F, V, wr[j]);

    // in-wave inclusive suffix scan: s_l = sum_{k>=l} g^(16(k-l)) V_k
    const int wv = tid >> 6, ln = tid & 63;
    float s = V;
    {
        const float F[6] = {Q1, Q2, Q4, Q8, Q16, Q32};
        #pragma unroll
        for (int k = 0; k < 6; ++k) {
            int off = 1 << k;
            float t = __shfl_down(s, off, 64);
            if (ln + off < 64) s = fmaf(F[k], t, s);
        }
    }
    if (ln == 0) waveS[wv] = s; // wave total (inclusive suffix at wave start)
    __syncthreads();

    // A_{wv+1} = inclusive suffix at start of next wave (Horner over g^1024)
    float Anext = 0.0f;
    for (int w2 = 3; w2 > wv; --w2) Anext = fmaf(G1024, Anext, waveS[w2]);

    // carry into this chunk's last element = S_{chunk+1}
    float snext = __shfl_down(s, 1, 64);
    if (ln == 63) snext = 0.0f;
    float carry = fmaf(pow_g16(63 - ln), Anext, snext);

    // final in-thread scan, write back (own chunk only -> no hazard)
    #pragma unroll
    for (int j = 15; j >= 0; --j) {
        carry = fmaf(GAMMA_F, carry, wr[j]);
        buf[pbase + j] = carry;
    }
    __syncthreads();

    // coalesced store
    #pragma unroll
    for (int j = 0; j < 16; ++j) {
        int idx = j * 256 + tid;
        cum[base + idx] = buf[idx + (idx >> 4)];
    }
}

// ---------------------------------------------------------------------------
// K2a: deterministic column partial sums of (cum - baselines).
// grid (T/256, 32): each block sums a 128-row chunk for 256 columns.
// ---------------------------------------------------------------------------
__global__ __launch_bounds__(256) void k_colpart(const float* __restrict__ cum,
                                                 const float* __restrict__ baselines,
                                                 float* __restrict__ partials) {
    const int t = blockIdx.x * 256 + threadIdx.x;
    const int r0 = blockIdx.y * 128;
    float sum = 0.0f;
    size_t p = (size_t)r0 * T_DIM + t;
    for (int r = 0; r < 128; ++r, p += T_DIM)
        sum += cum[p] - baselines[p];
    partials[blockIdx.y * T_DIM + t] = sum;
}

// K2b: reduce 32 partials per column -> column mean
__global__ __launch_bounds__(256) void k_colmean(const float* __restrict__ partials,
                                                 float* __restrict__ colmean) {
    const int t = blockIdx.x * 256 + threadIdx.x;
    float s = 0.0f;
    #pragma unroll
    for (int c = 0; c < 32; ++c) s += partials[c * T_DIM + t];
    colmean[t] = s * (1.0f / B_DIM);
}

// ---------------------------------------------------------------------------
// K3: per-row objective = sum_t clip(cum - base - colmean) * log_probs
// ---------------------------------------------------------------------------
__global__ __launch_bounds__(256) void k_obj(const float* __restrict__ cum,
                                             const float* __restrict__ baselines,
                                             const float* __restrict__ logp,
                                             const float* __restrict__ colmean,
                                             float* __restrict__ obj) {
    const int row = blockIdx.x, tid = threadIdx.x;
    const size_t base = (size_t)row * T_DIM;
    float acc = 0.0f;
    #pragma unroll
    for (int j = 0; j < 16; ++j) {
        int t = j * 256 + tid;
        float adv = cum[base + t] - baselines[base + t] - colmean[t];
        adv = fminf(fmaxf(adv, -CLIP_V), CLIP_V);
        acc = fmaf(adv, logp[base + t], acc);
    }
    #pragma unroll
    for (int off = 32; off > 0; off >>= 1) acc += __shfl_down(acc, off, 64);
    __shared__ float ws4[4];
    if ((tid & 63) == 0) ws4[tid >> 6] = acc;
    __syncthreads();
    if (tid == 0) obj[row] = (ws4[0] + ws4[1]) + (ws4[2] + ws4[3]);
}

extern "C" void kernel_launch(void* const* d_in, const int* in_sizes, int n_in,
                              void* d_out, int out_size, void* d_ws, size_t ws_size,
                              hipStream_t stream) {
    const float* log_probs = (const float*)d_in[0];
    const float* logits    = (const float*)d_in[1];
    const float* weight    = (const float*)d_in[2];
    const float* baselines = (const float*)d_in[3];

    float* obj = (float*)d_out;           // [B]
    float* cum = obj + B_DIM;             // [B*T]

    float* partials = (float*)d_ws;               // 32*T floats
    float* colmean  = partials + 32 * T_DIM;      // T floats (total ws: 540 KB)

    k_scan   <<<B_DIM,                 256, 0, stream>>>(logits, weight, cum);
    k_colpart<<<dim3(T_DIM / 256, 32), 256, 0, stream>>>(cum, baselines, partials);
    k_colmean<<<T_DIM / 256,           256, 0, stream>>>(partials, colmean);
    k_obj    <<<B_DIM,                 256, 0, stream>>>(cum, baselines, log_probs, colmean, obj);
}

// Round 2
// 279.127 us; speedup vs baseline: 1.0273x; 1.0273x over previous
//
#include <hip/hip_runtime.h>
#include <math.h>

#define B_DIM 4096
#define T_DIM 4096

constexpr float GAMMA_F = 0.99f;
constexpr float CLIP_V  = 5.0f;

// constexpr-folded gamma powers
constexpr float G2    = GAMMA_F * GAMMA_F; // g^2
constexpr float G4    = G2 * G2;           // g^4
constexpr float G8    = G4 * G4;           // g^8
constexpr float Q1    = G8 * G8;           // g^16
constexpr float Q2    = Q1 * Q1;           // g^32
constexpr float Q4    = Q2 * Q2;           // g^64
constexpr float Q8    = Q4 * Q4;           // g^128
constexpr float Q16   = Q8 * Q8;           // g^256
constexpr float Q32   = Q16 * Q16;         // g^512
constexpr float G1024 = Q32 * Q32;         // g^1024

// g^(16*e), e in [0,63], binary exponentiation (deterministic)
__device__ __forceinline__ float pow_g16(int e) {
    float f = 1.0f;
    if (e & 1)  f *= Q1;
    if (e & 2)  f *= Q2;
    if (e & 4)  f *= Q4;
    if (e & 8)  f *= Q8;
    if (e & 16) f *= Q16;
    if (e & 32) f *= Q32;
    return f;
}

// fast log_sigmoid: arg of log is in [1,2] -> v_log_f32 precision is plenty
__device__ __forceinline__ float lsig(float x) {
    return fminf(x, 0.0f) - __logf(1.0f + __expf(-fabsf(x)));
}

// ---------------------------------------------------------------------------
// K1: per-row reverse discounted scan. One block (256 thr) per row.
// Thread tid owns elements [tid*16, tid*16+16): direct float4 global loads
// (lane stride 64 B; lines fully consumed via L1 across the k=0..3 window),
// register Horner, wave shuffle-scan, cross-wave Horner, float4 stores.
// No LDS staging (R1: 75% VALUBusy, 1M bank-conflict cycles).
// ---------------------------------------------------------------------------
__global__ __launch_bounds__(256) void k_scan(const float4* __restrict__ logits,
                                              const float4* __restrict__ weight,
                                              float4* __restrict__ cum) {
    __shared__ float waveS[4];
    const int row = blockIdx.x;
    const int tid = threadIdx.x;
    const size_t base4 = (size_t)row * (T_DIM / 4) + (size_t)tid * 4;

    // load chunk, wr = weight * log_sigmoid(logits)
    float wr[16];
    #pragma unroll
    for (int k = 0; k < 4; ++k) {
        float4 x4 = logits[base4 + k];
        float4 w4 = weight[base4 + k];
        wr[4 * k + 0] = w4.x * lsig(x4.x);
        wr[4 * k + 1] = w4.y * lsig(x4.y);
        wr[4 * k + 2] = w4.z * lsig(x4.z);
        wr[4 * k + 3] = w4.w * lsig(x4.w);
    }

    // in-thread discounted suffix total V = sum_j g^j wr[j]
    float V = 0.0f;
    #pragma unroll
    for (int j = 15; j >= 0; --j) V = fmaf(GAMMA_F, V, wr[j]);

    // in-wave inclusive suffix scan: s_l = sum_{k>=l} g^(16(k-l)) V_k
    const int wv = tid >> 6, ln = tid & 63;
    float s = V;
    {
        const float F[6] = {Q1, Q2, Q4, Q8, Q16, Q32};
        #pragma unroll
        for (int k = 0; k < 6; ++k) {
            int off = 1 << k;
            float t = __shfl_down(s, off, 64);
            if (ln + off < 64) s = fmaf(F[k], t, s);
        }
    }
    if (ln == 0) waveS[wv] = s;
    __syncthreads();

    // inclusive suffix at start of next wave (Horner over g^1024)
    float Anext = 0.0f;
    for (int w2 = 3; w2 > wv; --w2) Anext = fmaf(G1024, Anext, waveS[w2]);

    // carry into this chunk's last element
    float snext = __shfl_down(s, 1, 64);
    if (ln == 63) snext = 0.0f;
    float carry = fmaf(pow_g16(63 - ln), Anext, snext);

    // final in-thread scan + float4 stores
    #pragma unroll
    for (int k = 3; k >= 0; --k) {
        float4 o4;
        o4.w = carry = fmaf(GAMMA_F, carry, wr[4 * k + 3]);
        o4.z = carry = fmaf(GAMMA_F, carry, wr[4 * k + 2]);
        o4.y = carry = fmaf(GAMMA_F, carry, wr[4 * k + 1]);
        o4.x = carry = fmaf(GAMMA_F, carry, wr[4 * k + 0]);
        cum[base4 + k] = o4;
    }
}

// zero colsum (ws is re-poisoned to 0xAA before every call)
__global__ __launch_bounds__(256) void k_zero(float* __restrict__ p) {
    p[blockIdx.x * 256 + threadIdx.x] = 0.0f;
}

// ---------------------------------------------------------------------------
// K2: column sums of (cum - baselines) via per-block partial + one atomic
// per column per block. grid (T/256, 128): 2048 blocks (8/CU), 32 rows each.
// ---------------------------------------------------------------------------
__global__ __launch_bounds__(256) void k_colsum(const float* __restrict__ cum,
                                                const float* __restrict__ baselines,
                                                float* __restrict__ colsum) {
    const int t = blockIdx.x * 256 + threadIdx.x;
    size_t p = (size_t)(blockIdx.y * 32) * T_DIM + t;
    float s0 = 0.0f, s1 = 0.0f, s2 = 0.0f, s3 = 0.0f;
    #pragma unroll
    for (int r = 0; r < 32; r += 4) {
        s0 += cum[p] - baselines[p];               p += T_DIM;
        s1 += cum[p] - baselines[p];               p += T_DIM;
        s2 += cum[p] - baselines[p];               p += T_DIM;
        s3 += cum[p] - baselines[p];               p += T_DIM;
    }
    atomicAdd(&colsum[t], (s0 + s1) + (s2 + s3));
}

// ---------------------------------------------------------------------------
// K3: obj[row] = sum_t clip(cum - base - colsum/B) * log_probs, float4 loads
// ---------------------------------------------------------------------------
__global__ __launch_bounds__(256) void k_obj(const float4* __restrict__ cum,
                                             const float4* __restrict__ baselines,
                                             const float4* __restrict__ logp,
                                             const float4* __restrict__ colsum,
                                             float* __restrict__ obj) {
    constexpr float invB = 1.0f / B_DIM;
    const int row = blockIdx.x, tid = threadIdx.x;
    const size_t base4 = (size_t)row * (T_DIM / 4);
    float acc = 0.0f;
    #pragma unroll
    for (int j = 0; j < 4; ++j) {
        int t4 = j * 256 + tid;
        float4 c = cum[base4 + t4];
        float4 b = baselines[base4 + t4];
        float4 l = logp[base4 + t4];
        float4 m = colsum[t4];
        float a0 = fminf(fmaxf(c.x - b.x - m.x * invB, -CLIP_V), CLIP_V);
        float a1 = fminf(fmaxf(c.y - b.y - m.y * invB, -CLIP_V), CLIP_V);
        float a2 = fminf(fmaxf(c.z - b.z - m.z * invB, -CLIP_V), CLIP_V);
        float a3 = fminf(fmaxf(c.w - b.w - m.w * invB, -CLIP_V), CLIP_V);
        acc = fmaf(a0, l.x, acc);
        acc = fmaf(a1, l.y, acc);
        acc = fmaf(a2, l.z, acc);
        acc = fmaf(a3, l.w, acc);
    }
    #pragma unroll
    for (int off = 32; off > 0; off >>= 1) acc += __shfl_down(acc, off, 64);
    __shared__ float ws4[4];
    if ((tid & 63) == 0) ws4[tid >> 6] = acc;
    __syncthreads();
    if (tid == 0) obj[row] = (ws4[0] + ws4[1]) + (ws4[2] + ws4[3]);
}

extern "C" void kernel_launch(void* const* d_in, const int* in_sizes, int n_in,
                              void* d_out, int out_size, void* d_ws, size_t ws_size,
                              hipStream_t stream) {
    const float* log_probs = (const float*)d_in[0];
    const float* logits    = (const float*)d_in[1];
    const float* weight    = (const float*)d_in[2];
    const float* baselines = (const float*)d_in[3];

    float* obj = (float*)d_out;       // [B]
    float* cum = obj + B_DIM;         // [B*T]
    float* colsum = (float*)d_ws;     // [T] (16 KB of ws)

    k_zero  <<<T_DIM / 256, 256, 0, stream>>>(colsum);
    k_scan  <<<B_DIM, 256, 0, stream>>>((const float4*)logits, (const float4*)weight,
                                        (float4*)cum);
    k_colsum<<<dim3(T_DIM / 256, 128), 256, 0, stream>>>(cum, baselines, colsum);
    k_obj   <<<B_DIM, 256, 0, stream>>>((const float4*)cum, (const float4*)baselines,
                                        (const float4*)log_probs, (const float4*)colsum, obj);
}